// Round 3
// baseline (666.891 us; speedup 1.0000x reference)
//
#include <hip/hip_runtime.h>
#include <stdint.h>

typedef int v4i __attribute__((ext_vector_type(4)));

#define QEPS 1e-8f

// s (at d_ws): [0]=bits absmax|x|, [1]=bits absmax|W|, [2]=int max|count|, [3]=pad
// d_ws+256: packed int8 B-operand wB[128 oc][16 ints] (k = kw*16 + (c*3+kh), 9 used/16)
// d_ws+256+8192: qb[128] float (integer-valued bias counts)

__global__ void k_init(unsigned int* s) { if (threadIdx.x < 4) s[threadIdx.x] = 0u; }

__global__ __launch_bounds__(256) void k_absmax(
    const float4* __restrict__ x, int n4, unsigned int* __restrict__ s) {
  __shared__ unsigned int red[256];
  const int t = threadIdx.x;
  unsigned int m = 0u;
  const int i = blockIdx.x * 256 + t;
  if (i < n4) {
    float4 v = x[i];
    m =        __float_as_uint(v.x) & 0x7fffffffu;
    m = max(m, __float_as_uint(v.y) & 0x7fffffffu);
    m = max(m, __float_as_uint(v.z) & 0x7fffffffu);
    m = max(m, __float_as_uint(v.w) & 0x7fffffffu);
  }
  red[t] = m;
  __syncthreads();
  for (int off = 128; off > 0; off >>= 1) {
    if (t < off) red[t] = max(red[t], red[t + off]);
    __syncthreads();
  }
  if (t == 0) atomicMax(&s[0], red[0]);
}

// Quantize+pack W once. Thread t = oc. k-order: byte j of group q = qw[tap j*3+q].
__global__ __launch_bounds__(128) void k_prep(
    const float* __restrict__ W, const float* __restrict__ b,
    unsigned int* __restrict__ s, int* __restrict__ wB, float* __restrict__ qb) {
  __shared__ float red[128];
  const int t = threadIdx.x;
  float w27[27];
  float m = 0.0f;
  #pragma unroll
  for (int k = 0; k < 27; ++k) { w27[k] = W[t * 27 + k]; m = fmaxf(m, fabsf(w27[k])); }
  red[t] = m;
  __syncthreads();
  for (int off = 64; off > 0; off >>= 1) {
    if (t < off) red[t] = fmaxf(red[t], red[t + off]);
    __syncthreads();
  }
  const float wmax = red[0];
  if (t == 0) s[1] = __float_as_uint(wmax);
  const float s_w  = fmaxf(wmax / 7.0f, QEPS);
  const float s_in = fmaxf(__uint_as_float(s[0]) / 127.0f, QEPS);

  int q[27];
  #pragma unroll
  for (int k = 0; k < 27; ++k) {
    float v = rintf(w27[k] / s_w);
    q[k] = (int)fminf(fmaxf(v, -7.0f), 7.0f);
  }
  #pragma unroll
  for (int qd = 0; qd < 4; ++qd) {
    #pragma unroll
    for (int w = 0; w < 4; ++w) {
      int word = 0;
      #pragma unroll
      for (int bi = 0; bi < 4; ++bi) {
        const int j = 4 * w + bi;
        const int val = (qd < 3 && j < 9) ? q[j * 3 + qd] : 0;
        word |= (val & 0xff) << (8 * bi);
      }
      wB[t * 16 + qd * 4 + w] = word;
    }
  }
  qb[t] = rintf(b[t] / (s_in * s_w));
}

// Implicit-GEMM conv via v_mfma_i32_16x16x64_i8. Block tile: 128 ow x 128 oc,
// one (n, oh). 4 waves; wave w owns M-subtiles {2w,2w+1} x all 8 N-subtiles.
// A-frag = one b128 LDS read of xcol[m+quad]; B-frags loaded once from global wB.
// PASS 0: int |count| max only. PASS 1: fake-quant + store NCHW f32.
template<int PASS>
__global__ __launch_bounds__(256, 3) void k_conv(
    const float* __restrict__ x, const int* __restrict__ wB,
    const float* __restrict__ qb, float* __restrict__ out,
    unsigned int* __restrict__ s) {
  __shared__ __align__(16) int xcol[132 * 4];  // [col][16B]: bytes 0..8 = q(x) taps, 9..15 = 0
  __shared__ int redi[256];

  const int t = threadIdx.x;
  const int owt = blockIdx.x & 1;
  const int r2 = blockIdx.x >> 1;
  const int n  = r2 & 15;
  const int oh = r2 >> 4;
  const int ow0 = owt * 128;

  const float s_in = fmaxf(__uint_as_float(s[0]) / 127.0f, QEPS);

  // stage quantized x columns (cols ow0 .. ow0+130, zero-pad OOB)
  if (t < 131) {
    const int gcol = ow0 + t;
    int qv[9];
    if (gcol < 224) {
      #pragma unroll
      for (int r = 0; r < 9; ++r) {
        const int c = r / 3, kh = r - c * 3;
        const float xv = x[((n * 3 + c) * 224 + (oh + kh)) * 224 + gcol];
        qv[r] = (int)fminf(fmaxf(rintf(xv / s_in), -128.0f), 127.0f);
      }
    } else {
      #pragma unroll
      for (int r = 0; r < 9; ++r) qv[r] = 0;
    }
    const int w0 = (qv[0] & 0xff) | (qv[1] & 0xff) << 8 | (qv[2] & 0xff) << 16 | (qv[3] & 0xff) << 24;
    const int w1 = (qv[4] & 0xff) | (qv[5] & 0xff) << 8 | (qv[6] & 0xff) << 16 | (qv[7] & 0xff) << 24;
    const int w2 = (qv[8] & 0xff);
    ((v4i*)xcol)[t] = (v4i){w0, w1, w2, 0};
  }

  const int lane = t & 63;
  const int wv   = t >> 6;
  const int l15  = lane & 15;
  const int quad = lane >> 4;

  // B-fragments + bias (global, L2-resident) — overlaps xcol staging
  v4i bfr[8];
  int qbi[8];
  #pragma unroll
  for (int nt = 0; nt < 8; ++nt) {
    bfr[nt] = ((const v4i*)wB)[(nt * 16 + l15) * 4 + quad];
    qbi[nt] = (int)qb[nt * 16 + l15];
  }

  __syncthreads();

  v4i afr[2];
  #pragma unroll
  for (int mt = 0; mt < 2; ++mt)
    afr[mt] = ((const v4i*)xcol)[(2 * wv + mt) * 16 + l15 + quad];

  v4i acc[2][8];
  #pragma unroll
  for (int mt = 0; mt < 2; ++mt)
    #pragma unroll
    for (int nt = 0; nt < 8; ++nt) acc[mt][nt] = (v4i){0, 0, 0, 0};

  #pragma unroll
  for (int mt = 0; mt < 2; ++mt)
    #pragma unroll
    for (int nt = 0; nt < 8; ++nt)
      acc[mt][nt] = __builtin_amdgcn_mfma_i32_16x16x64_i8(afr[mt], bfr[nt], acc[mt][nt], 0, 0, 0);

  // D layout: col(oc) = l15, row(ow) = quad*4 + reg
  if (PASS == 0) {
    int vm = 0;
    #pragma unroll
    for (int mt = 0; mt < 2; ++mt) {
      const int owb = ow0 + (2 * wv + mt) * 16 + quad * 4;
      #pragma unroll
      for (int nt = 0; nt < 8; ++nt) {
        #pragma unroll
        for (int r = 0; r < 4; ++r) {
          if (owb + r < 222) {
            const int v = acc[mt][nt][r] + qbi[nt];
            vm = max(vm, v < 0 ? -v : v);
          }
        }
      }
    }
    redi[t] = vm;
    __syncthreads();
    for (int off = 128; off > 0; off >>= 1) {
      if (t < off) redi[t] = max(redi[t], redi[t + off]);
      __syncthreads();
    }
    if (t == 0) atomicMax(&s[2], (unsigned int)redi[0]);
  } else {
    const int vmax = (int)s[2];
    const float s_w  = fmaxf(__uint_as_float(s[1]) / 7.0f, QEPS);
    const float s_b  = s_in * s_w;
    const float s_out = fmaxf((s_b * (float)vmax) / 127.0f, QEPS);
    const float h = s_b / s_out;
    #pragma unroll
    for (int mt = 0; mt < 2; ++mt) {
      const int owb = ow0 + (2 * wv + mt) * 16 + quad * 4;
      if (owb < 222) {  // even cutoff: float2 pairs never split
        #pragma unroll
        for (int nt = 0; nt < 8; ++nt) {
          const int oc = nt * 16 + l15;
          float o4[4];
          #pragma unroll
          for (int r = 0; r < 4; ++r) {
            const float vf = (float)(acc[mt][nt][r] + qbi[nt]);
            float q = rintf(vf * h);
            q = fminf(fmaxf(q, -128.0f), 127.0f);
            o4[r] = q * s_out;
          }
          float* p = out + ((n * 128 + oc) * 49284 + oh * 222 + owb);
          *(float2*)p = make_float2(o4[0], o4[1]);
          if (owb + 2 < 222) *(float2*)(p + 2) = make_float2(o4[2], o4[3]);
        }
      }
    }
  }
}

extern "C" void kernel_launch(void* const* d_in, const int* in_sizes, int n_in,
                              void* d_out, int out_size, void* d_ws, size_t ws_size,
                              hipStream_t stream) {
  const float* x = (const float*)d_in[0];
  const float* W = (const float*)d_in[1];
  const float* b = (const float*)d_in[2];
  float* out = (float*)d_out;

  unsigned int* s = (unsigned int*)d_ws;
  int*   wB = (int*)((char*)d_ws + 256);
  float* qb = (float*)((char*)d_ws + 256 + 8192);

  k_init<<<1, 64, 0, stream>>>(s);

  const int n4 = in_sizes[0] / 4;  // 602,112
  k_absmax<<<(n4 + 255) / 256, 256, 0, stream>>>((const float4*)x, n4, s);

  k_prep<<<1, 128, 0, stream>>>(W, b, s, wB, qb);

  const int nblk = 2 * 16 * 222;  // 7104
  k_conv<0><<<nblk, 256, 0, stream>>>(x, wB, qb, out, s);
  k_conv<1><<<nblk, 256, 0, stream>>>(x, wB, qb, out, s);
}

// Round 4
// 658.628 us; speedup vs baseline: 1.0125x; 1.0125x over previous
//
#include <hip/hip_runtime.h>
#include <stdint.h>

typedef int v4i __attribute__((ext_vector_type(4)));

#define QEPS 1e-8f

// s (at d_ws): [0]=bits absmax|x|, [1]=bits absmax|W|, [2]=int max|count|, [3]=pad
// d_ws+256: packed int8 B-operand wB[128 oc][16 ints] (k = kw*16 + (c*3+kh), 9 used/16)
// d_ws+256+8192: qb[128] float (integer-valued bias counts)

__global__ void k_init(unsigned int* s) { if (threadIdx.x < 4) s[threadIdx.x] = 0u; }

__global__ __launch_bounds__(256) void k_absmax(
    const float4* __restrict__ x, int n4, unsigned int* __restrict__ s) {
  __shared__ unsigned int red[256];
  const int t = threadIdx.x;
  unsigned int m = 0u;
  const int i = blockIdx.x * 256 + t;
  if (i < n4) {
    float4 v = x[i];
    m =        __float_as_uint(v.x) & 0x7fffffffu;
    m = max(m, __float_as_uint(v.y) & 0x7fffffffu);
    m = max(m, __float_as_uint(v.z) & 0x7fffffffu);
    m = max(m, __float_as_uint(v.w) & 0x7fffffffu);
  }
  red[t] = m;
  __syncthreads();
  for (int off = 128; off > 0; off >>= 1) {
    if (t < off) red[t] = max(red[t], red[t + off]);
    __syncthreads();
  }
  if (t == 0) atomicMax(&s[0], red[0]);
}

// Quantize+pack W once. Thread t = oc. B k-order: byte j of k-group q = qw[tap j*3+q].
__global__ __launch_bounds__(128) void k_prep(
    const float* __restrict__ W, const float* __restrict__ b,
    unsigned int* __restrict__ s, int* __restrict__ wB, float* __restrict__ qb) {
  __shared__ float red[128];
  const int t = threadIdx.x;
  float w27[27];
  float m = 0.0f;
  #pragma unroll
  for (int k = 0; k < 27; ++k) { w27[k] = W[t * 27 + k]; m = fmaxf(m, fabsf(w27[k])); }
  red[t] = m;
  __syncthreads();
  for (int off = 64; off > 0; off >>= 1) {
    if (t < off) red[t] = fmaxf(red[t], red[t + off]);
    __syncthreads();
  }
  const float wmax = red[0];
  if (t == 0) s[1] = __float_as_uint(wmax);
  const float s_w  = fmaxf(wmax / 7.0f, QEPS);
  const float s_in = fmaxf(__uint_as_float(s[0]) / 127.0f, QEPS);

  int q[27];
  #pragma unroll
  for (int k = 0; k < 27; ++k) {
    float v = rintf(w27[k] / s_w);
    q[k] = (int)fminf(fmaxf(v, -7.0f), 7.0f);
  }
  #pragma unroll
  for (int qd = 0; qd < 4; ++qd) {
    #pragma unroll
    for (int w = 0; w < 4; ++w) {
      int word = 0;
      #pragma unroll
      for (int bi = 0; bi < 4; ++bi) {
        const int j = 4 * w + bi;
        const int val = (qd < 3 && j < 9) ? q[j * 3 + qd] : 0;
        word |= (val & 0xff) << (8 * bi);
      }
      wB[t * 16 + qd * 4 + w] = word;
    }
  }
  qb[t] = rintf(b[t] / (s_in * s_w));
}

// Implicit-GEMM conv, v_mfma_i32_16x16x64_i8. Block: 128ow x 128oc x 3 oh rows.
// Grid: 2 owt x 16 n x 74 oh-chunks = 2368 blocks. wB fragments loaded once/block;
// xcol double-buffered so stage(j+1) overlaps MFMA(j). One barrier per row.
// PASS 0: |count| max only. PASS 1: fake-quant + store NCHW f32.
template<int PASS>
__global__ __launch_bounds__(256, 3) void k_conv(
    const float* __restrict__ x, const int* __restrict__ wB,
    const float* __restrict__ qb, float* __restrict__ out,
    unsigned int* __restrict__ s) {
  __shared__ __align__(16) int xcol[2][132 * 4];  // [buf][col][16B]: 9 tap bytes + 0-pad
  __shared__ int redi[256];

  const int t = threadIdx.x;
  const int owt = blockIdx.x & 1;
  const int r2 = blockIdx.x >> 1;
  const int n  = r2 & 15;
  const int oh0 = (r2 >> 4) * 3;
  const int ow0 = owt * 128;

  const float s_in = fmaxf(__uint_as_float(s[0]) / 127.0f, QEPS);

  const int lane = t & 63;
  const int wv   = t >> 6;
  const int l15  = lane & 15;
  const int quad = lane >> 4;

  // B-fragments + bias once per block (8 KB, L2-resident)
  v4i bfr[8];
  int qbi[8];
  #pragma unroll
  for (int nt = 0; nt < 8; ++nt) {
    bfr[nt] = ((const v4i*)wB)[(nt * 16 + l15) * 4 + quad];
    qbi[nt] = (int)qb[nt * 16 + l15];
  }

  float s_out = 1.0f, h = 1.0f;
  if (PASS == 1) {
    const int vmax = (int)s[2];
    const float s_w = fmaxf(__uint_as_float(s[1]) / 7.0f, QEPS);
    const float s_b = s_in * s_w;
    s_out = fmaxf((s_b * (float)vmax) / 127.0f, QEPS);
    h = s_b / s_out;
  }

  auto stage = [&](int oh, int buf) {
    if (t < 131) {
      const int gcol = ow0 + t;
      int qv[9];
      if (gcol < 224) {
        #pragma unroll
        for (int r = 0; r < 9; ++r) {
          const int c = r / 3, kh = r - c * 3;
          const float xv = x[((n * 3 + c) * 224 + (oh + kh)) * 224 + gcol];
          qv[r] = (int)fminf(fmaxf(rintf(xv / s_in), -128.0f), 127.0f);
        }
      } else {
        #pragma unroll
        for (int r = 0; r < 9; ++r) qv[r] = 0;
      }
      const int w0 = (qv[0] & 0xff) | (qv[1] & 0xff) << 8 | (qv[2] & 0xff) << 16 | (qv[3] & 0xff) << 24;
      const int w1 = (qv[4] & 0xff) | (qv[5] & 0xff) << 8 | (qv[6] & 0xff) << 16 | (qv[7] & 0xff) << 24;
      const int w2 = (qv[8] & 0xff);
      ((v4i*)xcol[buf])[t] = (v4i){w0, w1, w2, 0};
    }
  };

  stage(oh0, 0);

  int vm = 0;

  #pragma unroll
  for (int j = 0; j < 3; ++j) {
    __syncthreads();
    if (j < 2) stage(oh0 + j + 1, (j + 1) & 1);  // overlaps compute(j)
    const int oh = oh0 + j;
    const int buf = j & 1;

    v4i afr[2];
    #pragma unroll
    for (int mt = 0; mt < 2; ++mt)
      afr[mt] = ((const v4i*)xcol[buf])[(2 * wv + mt) * 16 + l15 + quad];

    v4i acc[2][8];
    #pragma unroll
    for (int mt = 0; mt < 2; ++mt)
      #pragma unroll
      for (int nt = 0; nt < 8; ++nt) acc[mt][nt] = (v4i){0, 0, 0, 0};

    #pragma unroll
    for (int mt = 0; mt < 2; ++mt)
      #pragma unroll
      for (int nt = 0; nt < 8; ++nt)
        acc[mt][nt] = __builtin_amdgcn_mfma_i32_16x16x64_i8(afr[mt], bfr[nt], acc[mt][nt], 0, 0, 0);

    // D layout: col(oc) = l15, row(ow) = quad*4 + reg
    if (PASS == 0) {
      #pragma unroll
      for (int mt = 0; mt < 2; ++mt) {
        const int owb = ow0 + (2 * wv + mt) * 16 + quad * 4;
        const int vv = 222 - owb;  // multiple-of-4 owb: vv is >=4, ==2, or <=0
        if (vv > 0) {
          #pragma unroll
          for (int nt = 0; nt < 8; ++nt) {
            #pragma unroll
            for (int r = 0; r < 4; ++r) {
              if (r < vv) {
                const int v = acc[mt][nt][r] + qbi[nt];
                vm = max(vm, v < 0 ? -v : v);
              }
            }
          }
        }
      }
    } else {
      #pragma unroll
      for (int mt = 0; mt < 2; ++mt) {
        const int owb = ow0 + (2 * wv + mt) * 16 + quad * 4;
        const int vv = 222 - owb;
        if (vv > 0) {
          #pragma unroll
          for (int nt = 0; nt < 8; ++nt) {
            const int oc = nt * 16 + l15;
            float o4[4];
            #pragma unroll
            for (int r = 0; r < 4; ++r) {
              const float vf = (float)(acc[mt][nt][r] + qbi[nt]);
              float q = rintf(vf * h);
              q = fminf(fmaxf(q, -128.0f), 127.0f);
              o4[r] = q * s_out;
            }
            float* p = out + ((n * 128 + oc) * 49284 + oh * 222 + owb);
            if (vv >= 4) {
              if ((oh & 1) == 0) {  // 16B-aligned (oh*222+owb ≡ 0 mod 4), wave-uniform
                *(float4*)p = make_float4(o4[0], o4[1], o4[2], o4[3]);
              } else {
                *(float2*)p       = make_float2(o4[0], o4[1]);
                *(float2*)(p + 2) = make_float2(o4[2], o4[3]);
              }
            } else {  // vv == 2
              *(float2*)p = make_float2(o4[0], o4[1]);
            }
          }
        }
      }
    }
  }

  if (PASS == 0) {
    __syncthreads();
    redi[t] = vm;
    __syncthreads();
    for (int off = 128; off > 0; off >>= 1) {
      if (t < off) redi[t] = max(redi[t], redi[t + off]);
      __syncthreads();
    }
    if (t == 0) atomicMax(&s[2], (unsigned int)redi[0]);
  }
}

extern "C" void kernel_launch(void* const* d_in, const int* in_sizes, int n_in,
                              void* d_out, int out_size, void* d_ws, size_t ws_size,
                              hipStream_t stream) {
  const float* x = (const float*)d_in[0];
  const float* W = (const float*)d_in[1];
  const float* b = (const float*)d_in[2];
  float* out = (float*)d_out;

  unsigned int* s = (unsigned int*)d_ws;
  int*   wB = (int*)((char*)d_ws + 256);
  float* qb = (float*)((char*)d_ws + 256 + 8192);

  k_init<<<1, 64, 0, stream>>>(s);

  const int n4 = in_sizes[0] / 4;  // 602,112
  k_absmax<<<(n4 + 255) / 256, 256, 0, stream>>>((const float4*)x, n4, s);

  k_prep<<<1, 128, 0, stream>>>(W, b, s, wB, qb);

  const int nblk = 2 * 16 * 74;  // 2368
  k_conv<0><<<nblk, 256, 0, stream>>>(x, wB, qb, out, s);
  k_conv<1><<<nblk, 256, 0, stream>>>(x, wB, qb, out, s);
}